// Round 11
// baseline (1581.346 us; speedup 1.0000x reference)
//
#include <hip/hip_runtime.h>
#include <stdint.h>

typedef unsigned short u16;
typedef float f32x4 __attribute__((ext_vector_type(4)));
typedef __bf16 bf16x8 __attribute__((ext_vector_type(8)));

#define B_ 4096
#define D_ 2048
#define U_ 2048
#define K_ 4096   // D + U
#define N_ 8192   // 4*U
#define NT_ 128   // K/32 K-tiles

__device__ __forceinline__ u16 f32_bf16(float f) {
  uint32_t u = __float_as_uint(f);
  u += 0x7FFFu + ((u >> 16) & 1u);
  return (u16)(u >> 16);
}
__device__ __forceinline__ float hsig(float x) {
  return fminf(fmaxf(0.2f * x + 0.5f, 0.0f), 1.0f);
}
__device__ __forceinline__ float ftanh(float x) {
  x = fminf(fmaxf(x, -15.0f), 15.0f);
  float e = __expf(2.0f * x);
  return (e - 1.0f) / (e + 1.0f);
}
__device__ __forceinline__ void gload16(const void* g, void* l) {
  __builtin_amdgcn_global_load_lds(
      (const __attribute__((address_space(1))) void*)g,
      (__attribute__((address_space(3))) void*)l,
      16, 0, 0);
}

// ---- cast A = [inputs | h_tm1] -> bf16 [4096][4096] ----
__global__ __launch_bounds__(256) void cast_a(const float* __restrict__ x,
                                              const float* __restrict__ h,
                                              u16* __restrict__ A) {
  int c = blockIdx.x * 256 + threadIdx.x;
  int m = c >> 9;
  int kc = (c & 511) << 3;
  const float* src = (kc < D_) ? (x + (size_t)m * D_ + kc)
                               : (h + (size_t)m * U_ + (kc - D_));
  float4 v0 = ((const float4*)src)[0];
  float4 v1 = ((const float4*)src)[1];
  u16 o[8] = { f32_bf16(v0.x), f32_bf16(v0.y), f32_bf16(v0.z), f32_bf16(v0.w),
               f32_bf16(v1.x), f32_bf16(v1.y), f32_bf16(v1.z), f32_bf16(v1.w) };
  *(uint4*)(A + (size_t)c * 8) = *(const uint4*)o;
}

// ---- cast + transpose + gate-interleave W -> Wt[n'][k] bf16 [8192][4096] ----
// n' = ublk*64 + g*16 + ul  where u = ublk*16 + ul, original col n = g*2048 + u
__global__ __launch_bounds__(256) void cast_wt(const float* __restrict__ kern,
                                               const float* __restrict__ rker,
                                               u16* __restrict__ Wt) {
  __shared__ u16 sW[64][68];
  const int t = threadIdx.x;
  const int bx = blockIdx.x;   // ublk 0..127
  const int by = blockIdx.y;   // k block 0..63
  const int k0 = by * 64;
  const float* src = (k0 < D_) ? kern : rker;
  const int krow0 = (k0 < D_) ? k0 : (k0 - D_);
#pragma unroll
  for (int i = 0; i < 4; ++i) {
    int c = i * 256 + t;
    int kl = c >> 4;
    int nq = c & 15;
    int g  = nq >> 2;
    int ul = (nq & 3) << 2;
    int n  = g * U_ + bx * 16 + ul;
    float4 v = *(const float4*)(src + (size_t)(krow0 + kl) * N_ + n);
    u16 p[4] = { f32_bf16(v.x), f32_bf16(v.y), f32_bf16(v.z), f32_bf16(v.w) };
    *(ushort4*)&sW[kl][g * 16 + ul] = *(const ushort4*)p;
  }
  __syncthreads();
#pragma unroll
  for (int j = 0; j < 2; ++j) {
    int c2 = j * 256 + t;
    int nl = c2 >> 3;
    int kc = c2 & 7;
    u16 p[8];
#pragma unroll
    for (int jj = 0; jj < 8; ++jj) p[jj] = sW[kc * 8 + jj][nl];
    *(uint4*)(Wt + ((size_t)bx * 64 + nl) * K_ + k0 + kc * 8) = *(const uint4*)p;
  }
}

// == 256x256 GEMM: 4-parity BK=32, double-buffered fragments, LDS||MFMA ==
// LDS: 4 parities x (A[256][32] 16K + B[256][32] 16K) = 128 KiB -> 1 block/CU
// (8 waves = 2/SIMD) REGARDLESS of registers. Hence __launch_bounds__(512,1):
// allocator cap 512 combined regs/wave (usage ~190 arch + 128 AGPR acc); the
// round-9 (512,2) cap of 256 combined forced the spill (WRITE_SIZE 3.9 GB).
// Hardware check: 2 waves/SIMD x ~320 regs = 640 <= 2048-reg SIMD pool.
// phys_chunk = logical ^ ((row>>1)&3): measured 0-conflict (rounds 3/6).
//
// Phase p (consumes reg-set CUR = parity p, read during phase p-1):
//   STAGE tile p+2 -> parity (p+2)%4
//   VMW(4): drain stage(p-1) -> parity p+1 complete in LDS (this wave)
//   s_barrier        -> ALL waves' parity-(p+1) stages complete
//   asm "" memory    -> compiler fence: next reads cannot hoist above barrier
//   issue 12 ds_reads of parity p+1 -> reg-set NXT   (no explicit lgkm wait;
//       SIInsertWaitcnts emits minimal counted lgkmcnt before each MFMA use)
//   32 MFMA on CUR   (overlaps the in-flight NXT reads)
//
// Safety: (RAW) reads of parity p+1 are runtime-after barrier(p), which is
// after every wave's VMW(4) drain of its parity-(p+1) stage loads. (WAR)
// parity q re-staged at phase q+2, issued after barrier(q+1); q's reads
// (issued phase q-1) are lgkm-landed before the last MFMA of phase q issues,
// which precedes that wave reaching barrier(q+1).
#define LDSA(par) ((par) * 32768)
#define LDSB(par) ((par) * 32768 + 16384)

#define STAGE4(par, t) do { \
  const u16* ga_ = Ab + (size_t)grow * K_ + (t) * 32 + gch8; \
  const u16* gb_ = Bb + (size_t)grow * K_ + (t) * 32 + gch8; \
  char* la_ = ldsc + LDSA(par) + wid * 1024; \
  char* lb_ = ldsc + LDSB(par) + wid * 1024; \
  gload16(ga_, la_); \
  gload16(ga_ + (size_t)128 * K_, la_ + 8192); \
  gload16(gb_, lb_); \
  gload16(gb_ + (size_t)128 * K_, lb_ + 8192); \
} while (0)

#define VMW(n) asm volatile("s_waitcnt vmcnt(" #n ")" ::: "memory")
#define MFMA16 __builtin_amdgcn_mfma_f32_16x16x32_bf16

#define READF(avX, bvX, par) do { \
  const char* pa_ = ldsc + LDSA(par) + aob; \
  const char* pb_ = ldsc + LDSB(par) + bob; \
  bvX[0] = *(const bf16x8*)(pb_); \
  bvX[1] = *(const bf16x8*)(pb_ + 1024); \
  bvX[2] = *(const bf16x8*)(pb_ + 2048); \
  bvX[3] = *(const bf16x8*)(pb_ + 3072); \
  _Pragma("unroll") \
  for (int m_ = 0; m_ < 8; ++m_) avX[m_] = *(const bf16x8*)(pa_ + m_ * 1024); \
} while (0)

#define G8S(avX, bvX, mA, mB) \
  acc[mA][0] = MFMA16(avX[mA], bvX[0], acc[mA][0], 0, 0, 0); \
  acc[mA][1] = MFMA16(avX[mA], bvX[1], acc[mA][1], 0, 0, 0); \
  acc[mA][2] = MFMA16(avX[mA], bvX[2], acc[mA][2], 0, 0, 0); \
  acc[mA][3] = MFMA16(avX[mA], bvX[3], acc[mA][3], 0, 0, 0); \
  acc[mB][0] = MFMA16(avX[mB], bvX[0], acc[mB][0], 0, 0, 0); \
  acc[mB][1] = MFMA16(avX[mB], bvX[1], acc[mB][1], 0, 0, 0); \
  acc[mB][2] = MFMA16(avX[mB], bvX[2], acc[mB][2], 0, 0, 0); \
  acc[mB][3] = MFMA16(avX[mB], bvX[3], acc[mB][3], 0, 0, 0);

#define PHASE(avC, bvC, avN, bvN, parN, RD, STAGE_STMT, VMW_STMT) do { \
  STAGE_STMT; \
  VMW_STMT; \
  __builtin_amdgcn_s_barrier(); \
  asm volatile("" ::: "memory"); \
  if (RD) { READF(avN, bvN, parN); } \
  __builtin_amdgcn_s_setprio(1); \
  G8S(avC, bvC, 0, 1); \
  G8S(avC, bvC, 2, 3); \
  G8S(avC, bvC, 4, 5); \
  G8S(avC, bvC, 6, 7); \
  __builtin_amdgcn_s_setprio(0); \
} while (0)

__global__ __launch_bounds__(512, 1) void lstm_gemm(const u16* __restrict__ A,
                                                    const u16* __restrict__ Wt,
                                                    const float* __restrict__ c_prev,
                                                    float* __restrict__ out) {
  __shared__ __align__(16) u16 lds[65536];   // 128 KiB
  char* ldsc = (char*)lds;
  const int tid  = threadIdx.x;
  const int lane = tid & 63;
  const int wid  = tid >> 6;
  const int wr   = wid >> 2;   // 0..1: 128-row slice
  const int wcn  = wid & 3;    // 0..3: 64-col slice (4 gates x 16 u)
  const int fr   = lane & 15;
  const int fq   = lane >> 4;

  // XCD-aware swizzle (512 % 8 == 0 -> bijective)
  const int orig = blockIdx.x;
  const int wg   = ((orig & 7) << 6) | (orig >> 3);
  const int bm   = wg & 15;
  const int bn   = wg >> 4;

  const u16* Ab = A  + (size_t)bm * 256 * K_;
  const u16* Bb = Wt + (size_t)bn * 256 * K_;

  // staging: thread -> (row, swizzled 16B chunk) of a [256][32] tile slice
  const int grow = tid >> 2;                                 // 0..127
  const int gch8 = (((tid & 3) ^ ((grow >> 1) & 3)) << 3);   // element offset
  // fragment reads: logical chunk fq at row r lives at fq ^ ((r>>1)&3)
  const int csw = (fq ^ ((fr >> 1) & 3)) << 4;
  const int aob = (wr * 128 + fr) * 64 + csw;   // + m*1024
  const int bob = (wcn * 64 + fr) * 64 + csw;   // + n*1024

  f32x4 acc[8][4] = {};   // [m-frag][gate] -> AGPRs
  bf16x8 av0[8], bv0[4], av1[8], bv1[4];

  // ---- prologue: stage tiles 0,1; drain tile0; barrier; read parity 0 ----
  STAGE4(0, 0);
  STAGE4(1, 1);
  VMW(4);
  __builtin_amdgcn_s_barrier();
  asm volatile("" ::: "memory");
  READF(av0, bv0, 0);

  for (int tb = 0; tb < NT_; tb += 4) {
    PHASE(av0, bv0, av1, bv1, 1, 1, { STAGE4(2, tb + 2); }, { VMW(4); });
    PHASE(av1, bv1, av0, bv0, 2, 1, { STAGE4(3, tb + 3); }, { VMW(4); });
    if (tb + 4 < NT_) {
      PHASE(av0, bv0, av1, bv1, 3, 1, { STAGE4(0, tb + 4); }, { VMW(4); });
      PHASE(av1, bv1, av0, bv0, 0, 1, { STAGE4(1, tb + 5); }, { VMW(4); });
    } else {
      PHASE(av0, bv0, av1, bv1, 3, 1, {}, { VMW(0); });
      PHASE(av1, bv1, av0, bv0, 0, 0, {}, {});
    }
  }

  // ---- fused LSTM epilogue (C/D 16x16: col=fr, row=fq*4+r) ----
  const int u  = (bn * 4 + wcn) * 16 + fr;
  const size_t BU = (size_t)B_ * U_;
#pragma unroll
  for (int mi = 0; mi < 8; ++mi) {
#pragma unroll
    for (int r = 0; r < 4; ++r) {
      int row = bm * 256 + wr * 128 + mi * 16 + fq * 4 + r;
      float zi = acc[mi][0][r], zf = acc[mi][1][r];
      float zc = acc[mi][2][r], zo = acc[mi][3][r];
      float iv = hsig(zi), fv = hsig(zf), ov = hsig(zo);
      size_t off = (size_t)row * U_ + u;
      float cp = c_prev[off];
      float cv = fv * cp + iv * ftanh(zc);
      float hv = ov * ftanh(cv);
      out[off]          = hv;
      out[BU + off]     = hv;
      out[2 * BU + off] = cv;
    }
  }
}

extern "C" void kernel_launch(void* const* d_in, const int* in_sizes, int n_in,
                              void* d_out, int out_size, void* d_ws, size_t ws_size,
                              hipStream_t stream) {
  const float* x  = (const float*)d_in[0];
  const float* h  = (const float*)d_in[1];
  const float* cp = (const float*)d_in[2];
  const float* kk = (const float*)d_in[3];
  const float* rk = (const float*)d_in[4];
  float* out = (float*)d_out;

  const size_t bytesA  = (size_t)B_ * K_ * 2;   // 32 MiB
  const size_t bytesWt = (size_t)N_ * K_ * 2;   // 64 MiB
  if (ws_size < bytesA + bytesWt) return;

  u16* Aws = (u16*)d_ws;
  u16* Wt  = (u16*)((char*)d_ws + bytesA);

  cast_a<<<(B_ * K_ / 8) / 256, 256, 0, stream>>>(x, h, Aws);
  cast_wt<<<dim3(N_ / 64, K_ / 64), 256, 0, stream>>>(kk, rk, Wt);
  lstm_gemm<<<dim3(512), dim3(512), 0, stream>>>(Aws, Wt, cp, out);
}

// Round 12
// 831.202 us; speedup vs baseline: 1.9025x; 1.9025x over previous
//
#include <hip/hip_runtime.h>
#include <stdint.h>

typedef unsigned short u16;
typedef float f32x4 __attribute__((ext_vector_type(4)));
typedef __bf16 bf16x8 __attribute__((ext_vector_type(8)));

#define B_ 4096
#define D_ 2048
#define U_ 2048
#define K_ 4096   // D + U
#define N_ 8192   // 4*U
#define NT_ 128   // K/32 K-tiles

__device__ __forceinline__ u16 f32_bf16(float f) {
  uint32_t u = __float_as_uint(f);
  u += 0x7FFFu + ((u >> 16) & 1u);
  return (u16)(u >> 16);
}
__device__ __forceinline__ float hsig(float x) {
  return fminf(fmaxf(0.2f * x + 0.5f, 0.0f), 1.0f);
}
__device__ __forceinline__ float ftanh(float x) {
  x = fminf(fmaxf(x, -15.0f), 15.0f);
  float e = __expf(2.0f * x);
  return (e - 1.0f) / (e + 1.0f);
}
__device__ __forceinline__ void gload16(const void* g, void* l) {
  __builtin_amdgcn_global_load_lds(
      (const __attribute__((address_space(1))) void*)g,
      (__attribute__((address_space(3))) void*)l,
      16, 0, 0);
}

// ---- cast A = [inputs | h_tm1] -> bf16 [4096][4096] ----
__global__ __launch_bounds__(256) void cast_a(const float* __restrict__ x,
                                              const float* __restrict__ h,
                                              u16* __restrict__ A) {
  int c = blockIdx.x * 256 + threadIdx.x;
  int m = c >> 9;
  int kc = (c & 511) << 3;
  const float* src = (kc < D_) ? (x + (size_t)m * D_ + kc)
                               : (h + (size_t)m * U_ + (kc - D_));
  float4 v0 = ((const float4*)src)[0];
  float4 v1 = ((const float4*)src)[1];
  u16 o[8] = { f32_bf16(v0.x), f32_bf16(v0.y), f32_bf16(v0.z), f32_bf16(v0.w),
               f32_bf16(v1.x), f32_bf16(v1.y), f32_bf16(v1.z), f32_bf16(v1.w) };
  *(uint4*)(A + (size_t)c * 8) = *(const uint4*)o;
}

// ---- cast + transpose + gate-interleave W -> Wt[n'][k] bf16 [8192][4096] ----
// n' = ublk*64 + g*16 + ul  where u = ublk*16 + ul, original col n = g*2048 + u
__global__ __launch_bounds__(256) void cast_wt(const float* __restrict__ kern,
                                               const float* __restrict__ rker,
                                               u16* __restrict__ Wt) {
  __shared__ u16 sW[64][68];
  const int t = threadIdx.x;
  const int bx = blockIdx.x;   // ublk 0..127
  const int by = blockIdx.y;   // k block 0..63
  const int k0 = by * 64;
  const float* src = (k0 < D_) ? kern : rker;
  const int krow0 = (k0 < D_) ? k0 : (k0 - D_);
#pragma unroll
  for (int i = 0; i < 4; ++i) {
    int c = i * 256 + t;
    int kl = c >> 4;
    int nq = c & 15;
    int g  = nq >> 2;
    int ul = (nq & 3) << 2;
    int n  = g * U_ + bx * 16 + ul;
    float4 v = *(const float4*)(src + (size_t)(krow0 + kl) * N_ + n);
    u16 p[4] = { f32_bf16(v.x), f32_bf16(v.y), f32_bf16(v.z), f32_bf16(v.w) };
    *(ushort4*)&sW[kl][g * 16 + ul] = *(const ushort4*)p;
  }
  __syncthreads();
#pragma unroll
  for (int j = 0; j < 2; ++j) {
    int c2 = j * 256 + t;
    int nl = c2 >> 3;
    int kc = c2 & 7;
    u16 p[8];
#pragma unroll
    for (int jj = 0; jj < 8; ++jj) p[jj] = sW[kc * 8 + jj][nl];
    *(uint4*)(Wt + ((size_t)bx * 64 + nl) * K_ + k0 + kc * 8) = *(const uint4*)p;
  }
}

// ==== 256x256 GEMM: 4-parity BK=32, compiler partial-lgkm LDS||MFMA ====
// LDS: 4 parities x (A[256][32] 16K + B[256][32] 16K) = 128 KiB, 1 block/CU.
// Register budget: 512-thread block -> regsPerBlock 131072 / 512 = 256
// combined VGPR+AGPR per wave (HARD HW cap; rounds 9/11 proved launch_bounds
// can't lift it). acc 128 AGPR + ~128 VGPR fits exactly (r6-proven).
// Fragments single-buffered; overlap comes from COUNTED PARTIAL lgkm waits.
//
// Phase p:
//   s_barrier        -> parity p globally staged (every wave's VMW(4) at
//                       phase p-1 drained its parity-p stage pre-barrier)
//   asm "" memory    -> reads below cannot hoist above the barrier (r8 fix)
//   READF(p): 12 ds_reads (bv first, then av; no explicit lgkm drain)
//   STAGE tile p+2 -> parity (p+2)%4
//   VMW(4): queue = [stage@p-1 (par p+1), stage@p (par p+2)] = 8 -> drain
//           oldest 4 = parity p+1 landed (this wave) before next barrier
//   32 MFMA: compiler emits partial lgkmcnt(N) -> first G8 starts after 6
//           reads land; remaining LDS service overlaps MFMA issue (the
//           round-6 serialization - lgkmcnt(0) full drain - eliminated)
//
// WAR: stage(par p+2 = p-2 mod 4) at phase p vs readers at phase p-2: their
// reads are lgkm-landed before their last MFMA issues, which precedes their
// barrier(start p-1), which precedes barrier(start p), which precedes this
// stage's issue. Two barriers of margin.
#define LDSA(par) ((par) * 32768)
#define LDSB(par) ((par) * 32768 + 16384)

#define STAGE4(par, t) do { \
  const u16* ga_ = Ab + (size_t)grow * K_ + (t) * 32 + gch8; \
  const u16* gb_ = Bb + (size_t)grow * K_ + (t) * 32 + gch8; \
  char* la_ = ldsc + LDSA(par) + wid * 1024; \
  char* lb_ = ldsc + LDSB(par) + wid * 1024; \
  gload16(ga_, la_); \
  gload16(ga_ + (size_t)128 * K_, la_ + 8192); \
  gload16(gb_, lb_); \
  gload16(gb_ + (size_t)128 * K_, lb_ + 8192); \
} while (0)

#define VMW(n) asm volatile("s_waitcnt vmcnt(" #n ")" ::: "memory")
#define MFMA16 __builtin_amdgcn_mfma_f32_16x16x32_bf16

#define G8(mA, mB) \
  acc[mA][0] = MFMA16(av[mA], bv[0], acc[mA][0], 0, 0, 0); \
  acc[mA][1] = MFMA16(av[mA], bv[1], acc[mA][1], 0, 0, 0); \
  acc[mA][2] = MFMA16(av[mA], bv[2], acc[mA][2], 0, 0, 0); \
  acc[mA][3] = MFMA16(av[mA], bv[3], acc[mA][3], 0, 0, 0); \
  acc[mB][0] = MFMA16(av[mB], bv[0], acc[mB][0], 0, 0, 0); \
  acc[mB][1] = MFMA16(av[mB], bv[1], acc[mB][1], 0, 0, 0); \
  acc[mB][2] = MFMA16(av[mB], bv[2], acc[mB][2], 0, 0, 0); \
  acc[mB][3] = MFMA16(av[mB], bv[3], acc[mB][3], 0, 0, 0);

#define PHASE(par, STAGE_STMT, VMW_STMT) do { \
  __builtin_amdgcn_s_barrier(); \
  asm volatile("" ::: "memory"); \
  const char* pa_ = ldsc + LDSA(par) + aob; \
  const char* pb_ = ldsc + LDSB(par) + bob; \
  bv[0] = *(const bf16x8*)(pb_); \
  bv[1] = *(const bf16x8*)(pb_ + 1024); \
  bv[2] = *(const bf16x8*)(pb_ + 2048); \
  bv[3] = *(const bf16x8*)(pb_ + 3072); \
  av[0] = *(const bf16x8*)(pa_); \
  av[1] = *(const bf16x8*)(pa_ + 1024); \
  av[2] = *(const bf16x8*)(pa_ + 2048); \
  av[3] = *(const bf16x8*)(pa_ + 3072); \
  av[4] = *(const bf16x8*)(pa_ + 4096); \
  av[5] = *(const bf16x8*)(pa_ + 5120); \
  av[6] = *(const bf16x8*)(pa_ + 6144); \
  av[7] = *(const bf16x8*)(pa_ + 7168); \
  STAGE_STMT; \
  VMW_STMT; \
  __builtin_amdgcn_s_setprio(1); \
  G8(0, 1); \
  G8(2, 3); \
  G8(4, 5); \
  G8(6, 7); \
  __builtin_amdgcn_s_setprio(0); \
} while (0)

__global__ __launch_bounds__(512, 2) void lstm_gemm(const u16* __restrict__ A,
                                                    const u16* __restrict__ Wt,
                                                    const float* __restrict__ c_prev,
                                                    float* __restrict__ out) {
  __shared__ __align__(16) u16 lds[65536];   // 128 KiB
  char* ldsc = (char*)lds;
  const int tid  = threadIdx.x;
  const int lane = tid & 63;
  const int wid  = tid >> 6;
  const int wr   = wid >> 2;   // 0..1: 128-row slice
  const int wcn  = wid & 3;    // 0..3: 64-col slice (4 gates x 16 u)
  const int fr   = lane & 15;
  const int fq   = lane >> 4;

  // XCD-aware swizzle (512 % 8 == 0 -> bijective)
  const int orig = blockIdx.x;
  const int wg   = ((orig & 7) << 6) | (orig >> 3);
  const int bm   = wg & 15;
  const int bn   = wg >> 4;

  const u16* Ab = A  + (size_t)bm * 256 * K_;
  const u16* Bb = Wt + (size_t)bn * 256 * K_;

  // staging: thread -> (row, swizzled 16B chunk) of a [256][32] tile slice
  const int grow = tid >> 2;                                 // 0..127
  const int gch8 = (((tid & 3) ^ ((grow >> 1) & 3)) << 3);   // element offset
  // fragment reads: logical chunk fq at row r lives at fq ^ ((r>>1)&3)
  const int csw = (fq ^ ((fr >> 1) & 3)) << 4;
  const int aob = (wr * 128 + fr) * 64 + csw;   // + m*1024
  const int bob = (wcn * 64 + fr) * 64 + csw;   // + n*1024

  f32x4 acc[8][4] = {};   // [m-frag][gate] -> AGPRs
  bf16x8 av[8], bv[4];

  // ---- prologue: stage tiles 0,1; drain tile0 (queue 8 -> 4) ----
  STAGE4(0, 0);
  STAGE4(1, 1);
  VMW(4);

  for (int tb = 0; tb < NT_; tb += 4) {
    PHASE(0, { STAGE4(2, tb + 2); }, { VMW(4); });
    PHASE(1, { STAGE4(3, tb + 3); }, { VMW(4); });
    if (tb + 4 < NT_) {
      PHASE(2, { STAGE4(0, tb + 4); }, { VMW(4); });
      PHASE(3, { STAGE4(1, tb + 5); }, { VMW(4); });
    } else {
      PHASE(2, {}, { VMW(0); });   // drain tail stage (parity 3, tile 127)
      PHASE(3, {}, {});
    }
  }

  // ---- fused LSTM epilogue (C/D 16x16: col=fr, row=fq*4+r) ----
  const int u  = (bn * 4 + wcn) * 16 + fr;
  const size_t BU = (size_t)B_ * U_;
#pragma unroll
  for (int mi = 0; mi < 8; ++mi) {
#pragma unroll
    for (int r = 0; r < 4; ++r) {
      int row = bm * 256 + wr * 128 + mi * 16 + fq * 4 + r;
      float zi = acc[mi][0][r], zf = acc[mi][1][r];
      float zc = acc[mi][2][r], zo = acc[mi][3][r];
      float iv = hsig(zi), fv = hsig(zf), ov = hsig(zo);
      size_t off = (size_t)row * U_ + u;
      float cp = c_prev[off];
      float cv = fv * cp + iv * ftanh(zc);
      float hv = ov * ftanh(cv);
      out[off]          = hv;
      out[BU + off]     = hv;
      out[2 * BU + off] = cv;
    }
  }
}

extern "C" void kernel_launch(void* const* d_in, const int* in_sizes, int n_in,
                              void* d_out, int out_size, void* d_ws, size_t ws_size,
                              hipStream_t stream) {
  const float* x  = (const float*)d_in[0];
  const float* h  = (const float*)d_in[1];
  const float* cp = (const float*)d_in[2];
  const float* kk = (const float*)d_in[3];
  const float* rk = (const float*)d_in[4];
  float* out = (float*)d_out;

  const size_t bytesA  = (size_t)B_ * K_ * 2;   // 32 MiB
  const size_t bytesWt = (size_t)N_ * K_ * 2;   // 64 MiB
  if (ws_size < bytesA + bytesWt) return;

  u16* Aws = (u16*)d_ws;
  u16* Wt  = (u16*)((char*)d_ws + bytesA);

  cast_a<<<(B_ * K_ / 8) / 256, 256, 0, stream>>>(x, h, Aws);
  cast_wt<<<dim3(N_ / 64, K_ / 64), 256, 0, stream>>>(kk, rk, Wt);
  lstm_gemm<<<dim3(512), dim3(512), 0, stream>>>(Aws, Wt, cp, out);
}

// Round 13
// 329.872 us; speedup vs baseline: 4.7938x; 2.5198x over previous
//
#include <hip/hip_runtime.h>
#include <stdint.h>

typedef unsigned short u16;
typedef float f32x4 __attribute__((ext_vector_type(4)));
typedef __bf16 bf16x8 __attribute__((ext_vector_type(8)));

#define B_ 4096
#define D_ 2048
#define U_ 2048
#define K_ 4096   // D + U
#define N_ 8192   // 4*U
#define NT_ 128   // K/32 K-tiles

__device__ __forceinline__ u16 f32_bf16(float f) {
  uint32_t u = __float_as_uint(f);
  u += 0x7FFFu + ((u >> 16) & 1u);
  return (u16)(u >> 16);
}
__device__ __forceinline__ float hsig(float x) {
  return fminf(fmaxf(0.2f * x + 0.5f, 0.0f), 1.0f);
}
__device__ __forceinline__ float ftanh(float x) {
  x = fminf(fmaxf(x, -15.0f), 15.0f);
  float e = __expf(2.0f * x);
  return (e - 1.0f) / (e + 1.0f);
}
__device__ __forceinline__ void gload16(const void* g, void* l) {
  __builtin_amdgcn_global_load_lds(
      (const __attribute__((address_space(1))) void*)g,
      (__attribute__((address_space(3))) void*)l,
      16, 0, 0);
}

// ---- cast A = [inputs | h_tm1] -> bf16 [4096][4096] ----
__global__ __launch_bounds__(256) void cast_a(const float* __restrict__ x,
                                              const float* __restrict__ h,
                                              u16* __restrict__ A) {
  int c = blockIdx.x * 256 + threadIdx.x;
  int m = c >> 9;
  int kc = (c & 511) << 3;
  const float* src = (kc < D_) ? (x + (size_t)m * D_ + kc)
                               : (h + (size_t)m * U_ + (kc - D_));
  float4 v0 = ((const float4*)src)[0];
  float4 v1 = ((const float4*)src)[1];
  u16 o[8] = { f32_bf16(v0.x), f32_bf16(v0.y), f32_bf16(v0.z), f32_bf16(v0.w),
               f32_bf16(v1.x), f32_bf16(v1.y), f32_bf16(v1.z), f32_bf16(v1.w) };
  *(uint4*)(A + (size_t)c * 8) = *(const uint4*)o;
}

// ---- cast + transpose + gate-interleave W -> Wt[n'][k] bf16 [8192][4096] ----
// n' = ublk*128 + g*32 + ul  where u = ublk*32 + ul, original col n = g*2048+u
// (round-4-proven period-128 version)
__global__ __launch_bounds__(256) void cast_wt(const float* __restrict__ kern,
                                               const float* __restrict__ rker,
                                               u16* __restrict__ Wt) {
  __shared__ u16 sW[64][134];    // odd dword stride -> no write conflicts
  const int t = threadIdx.x;
  const int bx = blockIdx.x;     // ublk 0..63
  const int by = blockIdx.y;     // k-block 0..63
  const int k0 = by * 64;
  const float* src = (k0 < D_) ? kern : rker;
  const int krow0 = (k0 < D_) ? k0 : (k0 - D_);
#pragma unroll
  for (int i = 0; i < 8; ++i) {
    int q  = i * 256 + t;        // float4 task 0..2047
    int kl = q >> 5;             // 0..63 local k row
    int cc = q & 31;             // float4 index within 128 n'-cols
    int g  = cc >> 3;
    int n  = g * U_ + bx * 32 + (cc & 7) * 4;
    float4 v = *(const float4*)(src + (size_t)(krow0 + kl) * N_ + n);
    u16 p[4] = { f32_bf16(v.x), f32_bf16(v.y), f32_bf16(v.z), f32_bf16(v.w) };
    *(ushort4*)&sW[kl][cc * 4] = *(const ushort4*)p;
  }
  __syncthreads();
#pragma unroll
  for (int j = 0; j < 4; ++j) {
    int c2 = j * 256 + t;        // task 0..1023
    int r  = c2 >> 3;            // 0..127 local n'
    int kc = c2 & 7;             // 8-elem chunk along k
    u16 p[8];
#pragma unroll
    for (int jj = 0; jj < 8; ++jj) p[jj] = sW[kc * 8 + jj][r];
    *(uint4*)(Wt + ((size_t)bx * 128 + r) * K_ + k0 + kc * 8) = *(const uint4*)p;
  }
}

// == 128x256 GEMM, 256 thr (4 waves), 3-parity BK=32, 2 blocks/CU overlap ==
// LDS: 3 x (A[128][32] 8K + B[256][32] 16K) = 72 KiB -> 2 blocks/CU. The two
// co-resident blocks have INDEPENDENT barriers: when one stalls at its
// barrier/lgkm drain, the other's waves feed the MFMA pipe (m114 overlap) --
// no cross-phase register pipelining needed, so single-buffered fragments.
// Registers: 256-thr block -> hard cap 131072/256 = 512/wave; usage
// acc 128 AGPR + frags 48 + addr ~50 => no spill possible (r12 fix).
// phys_chunk = logical ^ ((row>>1)&3): measured 0-conflict (rounds 3/6).
//
// Phase p: [barrier] [fence] [12 ds_reads parity p%3] [STAGE tile p+2 ->
// parity (p+2)%3] [VMW(6): drains stage(p-1) = tile p+1] [32 MFMA; compiler
// emits counted partial lgkmcnt] [lgkmcnt(0): free (reads consumed), closes
// WAR formally before next barrier].
// RAW: tile p staged at p-2, drained by VMW(6) at p-1 (all waves, pre-
// barrier(p)). WAR: stage at p overwrites parity read at p-1; those reads
// landed before lgkm(0)@p-1 < barrier(p) < stage issue.
#define PA(par) ((par) * 24576)
#define PB(par) ((par) * 24576 + 8192)

#define STAGE6(par, t) do { \
  const u16* ga_ = Ab + (size_t)grow * K_ + (t) * 32 + gch8; \
  const u16* gb_ = Bb + (size_t)grow * K_ + (t) * 32 + gch8; \
  char* la_ = ldsc + PA(par) + wid * 1024; \
  char* lb_ = ldsc + PB(par) + wid * 1024; \
  gload16(ga_,                    la_); \
  gload16(ga_ + (size_t)64 * K_,  la_ + 4096); \
  gload16(gb_,                    lb_); \
  gload16(gb_ + (size_t)64 * K_,  lb_ + 4096); \
  gload16(gb_ + (size_t)128 * K_, lb_ + 8192); \
  gload16(gb_ + (size_t)192 * K_, lb_ + 12288); \
} while (0)

#define VMW(n) asm volatile("s_waitcnt vmcnt(" #n ")" ::: "memory")
#define MFMA16 __builtin_amdgcn_mfma_f32_16x16x32_bf16

#define PHASE(par, STAGE_STMT, VMW_STMT) do { \
  __builtin_amdgcn_s_barrier(); \
  asm volatile("" ::: "memory"); \
  const char* pa_ = ldsc + PA(par) + aob; \
  const char* pb_ = ldsc + PB(par) + bob; \
  av[0] = *(const bf16x8*)(pa_); \
  bv[0] = *(const bf16x8*)(pb_); \
  bv[1] = *(const bf16x8*)(pb_ + 1024); \
  bv[2] = *(const bf16x8*)(pb_ + 2048); \
  bv[3] = *(const bf16x8*)(pb_ + 3072); \
  bv[4] = *(const bf16x8*)(pb_ + 4096); \
  bv[5] = *(const bf16x8*)(pb_ + 5120); \
  bv[6] = *(const bf16x8*)(pb_ + 6144); \
  bv[7] = *(const bf16x8*)(pb_ + 7168); \
  av[1] = *(const bf16x8*)(pa_ + 1024); \
  av[2] = *(const bf16x8*)(pa_ + 2048); \
  av[3] = *(const bf16x8*)(pa_ + 3072); \
  STAGE_STMT; \
  VMW_STMT; \
  __builtin_amdgcn_s_setprio(1); \
  _Pragma("unroll") \
  for (int m_ = 0; m_ < 4; ++m_) { \
    _Pragma("unroll") \
    for (int n_ = 0; n_ < 8; ++n_) \
      acc[m_][n_] = MFMA16(av[m_], bv[n_], acc[m_][n_], 0, 0, 0); \
  } \
  __builtin_amdgcn_s_setprio(0); \
  asm volatile("s_waitcnt lgkmcnt(0)" ::: "memory"); \
} while (0)

__global__ __launch_bounds__(256, 2) void lstm_gemm(const u16* __restrict__ A,
                                                    const u16* __restrict__ Wt,
                                                    const float* __restrict__ c_prev,
                                                    float* __restrict__ out) {
  __shared__ __align__(16) u16 lds[36864];   // 72 KiB
  char* ldsc = (char*)lds;
  const int tid  = threadIdx.x;
  const int lane = tid & 63;
  const int wid  = tid >> 6;   // 0..3
  const int wr   = wid >> 1;   // 0..1: 64-row slice
  const int wcn  = wid & 1;    // 0..1: 128-col slice (4 gates x 32 u)
  const int fr   = lane & 15;
  const int fq   = lane >> 4;

  // XCD-aware swizzle (1024 % 8 == 0 -> bijective); bm fastest per XCD so
  // the 2 concurrent bn B-panels (4 MB) stay L2-resident; A L3-resident.
  const int orig = blockIdx.x;
  const int wg   = ((orig & 7) << 7) | (orig >> 3);
  const int bm   = wg & 31;    // 0..31 (rows of 128)
  const int bn   = wg >> 5;    // 0..31 (cols of 256)

  const u16* Ab = A  + (size_t)bm * 128 * K_;
  const u16* Bb = Wt + (size_t)bn * 256 * K_;

  // staging: thread -> (row, swizzled 16B chunk) of a [64][32] band
  const int grow = tid >> 2;                                 // 0..63
  const int gch8 = (((tid & 3) ^ ((grow >> 1) & 3)) << 3);   // element offset
  // fragment reads: logical chunk fq at row r lives at fq ^ ((r>>1)&3)
  const int csw = (fq ^ ((fr >> 1) & 3)) << 4;
  const int aob = (wr * 64 + fr) * 64 + csw;     // + m*1024
  const int bob = (wcn * 128 + fr) * 64 + csw;   // + n*1024

  f32x4 acc[4][8] = {};   // [m-frag][n-frag] -> AGPRs
  bf16x8 av[4], bv[8];

  // ---- prologue: stage tiles 0,1 -> parities 0,1; drain tile0 ----
  STAGE6(0, 0);
  STAGE6(1, 1);
  VMW(6);

  for (int tb = 0; tb < 126; tb += 3) {
    PHASE(0, { STAGE6(2, tb + 2); }, { VMW(6); });
    PHASE(1, { STAGE6(0, tb + 3); }, { VMW(6); });
    PHASE(2, { STAGE6(1, tb + 4); }, { VMW(6); });
  }
  PHASE(0, {}, { VMW(0); });   // phase 126: drain tile 127's stage
  PHASE(1, {}, {});            // phase 127

  // ---- fused LSTM epilogue ----
  // col in wave-tile: c = n*16 + fr; gate = n>>1; u-half h = n&1;
  // u = (bn*2+wcn)*32 + h*16 + fr. C/D 16x16: row = fq*4 + r.
  const int ub = (bn * 2 + wcn) * 32;
  const size_t BU = (size_t)B_ * U_;
#pragma unroll
  for (int mi = 0; mi < 4; ++mi) {
#pragma unroll
    for (int h = 0; h < 2; ++h) {
#pragma unroll
      for (int r = 0; r < 4; ++r) {
        int row = bm * 128 + wr * 64 + mi * 16 + fq * 4 + r;
        int u   = ub + h * 16 + fr;
        float zi = acc[mi][0 + h][r], zf = acc[mi][2 + h][r];
        float zc = acc[mi][4 + h][r], zo = acc[mi][6 + h][r];
        float iv = hsig(zi), fv = hsig(zf), ov = hsig(zo);
        size_t off = (size_t)row * U_ + u;
        float cp = c_prev[off];
        float cv = fv * cp + iv * ftanh(zc);
        float hv = ov * ftanh(cv);
        out[off]          = hv;
        out[BU + off]     = hv;
        out[2 * BU + off] = cv;
      }
    }
  }
}

extern "C" void kernel_launch(void* const* d_in, const int* in_sizes, int n_in,
                              void* d_out, int out_size, void* d_ws, size_t ws_size,
                              hipStream_t stream) {
  const float* x  = (const float*)d_in[0];
  const float* h  = (const float*)d_in[1];
  const float* cp = (const float*)d_in[2];
  const float* kk = (const float*)d_in[3];
  const float* rk = (const float*)d_in[4];
  float* out = (float*)d_out;

  const size_t bytesA  = (size_t)B_ * K_ * 2;   // 32 MiB
  const size_t bytesWt = (size_t)N_ * K_ * 2;   // 64 MiB
  if (ws_size < bytesA + bytesWt) return;

  u16* Aws = (u16*)d_ws;
  u16* Wt  = (u16*)((char*)d_ws + bytesA);

  cast_a<<<(B_ * K_ / 8) / 256, 256, 0, stream>>>(x, h, Aws);
  cast_wt<<<dim3(64, 64), 256, 0, stream>>>(kk, rk, Wt);
  lstm_gemm<<<dim3(1024), dim3(256), 0, stream>>>(Aws, Wt, cp, out);
}